// Round 1
// baseline (998.613 us; speedup 1.0000x reference)
//
#include <hip/hip_runtime.h>
#include <cstdint>
#include <cstddef>

// Problem constants (B=2048, H=4096, K=4)
#define HD   4096
#define BSZ  2048

// ---------------------------------------------------------------------------
// R2: GEMM1/GEMM2 moved to the 256x256 8-phase counted-vmcnt template
// (m201-class): 512 thr / 8 waves (2M x 4N), BK=64, double-buffered LDS
// (128 KiB), raw s_barrier + asm vmcnt(4) (never 0 in steady state),
// setprio(1) around MFMA, XCD-aware bijective block swizzle.
// GEMM3 (N=4096 -> only 128 blocks at 256^2) stays on the 128^2 kernel.
// ---------------------------------------------------------------------------
constexpr int BM = 128, BN = 128, BKT = 64;

typedef __bf16 bf16x8 __attribute__((ext_vector_type(8)));
typedef float  f32x4  __attribute__((ext_vector_type(4)));

__device__ __forceinline__ unsigned short f2bf(float f) {
  unsigned u = __float_as_uint(f);
  u += 0x7fffu + ((u >> 16) & 1u);   // RNE
  return (unsigned short)(u >> 16);
}
__device__ __forceinline__ float bf2f(unsigned short s) {
  return __uint_as_float(((unsigned)s) << 16);
}

#define AS1(p) ((__attribute__((address_space(1))) void*)(void*)(p))
#define AS3(p) ((__attribute__((address_space(3))) void*)(p))

// ---------------------------------------------------------------- converts
__global__ void cvt_f32_to_bf16(const float4* __restrict__ src,
                                ushort4* __restrict__ dst, int n4) {
  int i = blockIdx.x * blockDim.x + threadIdx.x;
  if (i >= n4) return;
  float4 v = src[i];
  ushort4 o;
  o.x = f2bf(v.x); o.y = f2bf(v.y); o.z = f2bf(v.z); o.w = f2bf(v.w);
  dst[i] = o;
}

// ---------------------------------------------------------------- 128^2 GEMM
// (kept for GEMM3 / MODE 0 only — unchanged from R1, harness-verified)
template <int MODE>
__global__ __launch_bounds__(256) void gemm_bt(
    const unsigned short* __restrict__ A, const unsigned short* __restrict__ Bw,
    float* __restrict__ outf, unsigned short* __restrict__ gate_bf,
    float* __restrict__ xrec, int M, int N, int K) {
  __shared__ unsigned short smA[BM * BKT];
  __shared__ unsigned short smB[BN * BKT];
  const int tid  = threadIdx.x;
  const int wid  = tid >> 6;
  const int lane = tid & 63;
  const int wm = wid >> 1, wn = wid & 1;
  const int l16 = lane & 15, q = lane >> 4;
  const int bx = blockIdx.x, by = blockIdx.y;
  const int srow = tid >> 3;
  const int scol = (((tid & 7) ^ ((tid >> 3) & 7)) * 8);
  const unsigned short* Ab = A + (size_t)(by * BM) * K + scol;
  const unsigned short* Bb = Bw + (size_t)(bx * BN) * K + scol;
  const int ldsbase = (wid * 8) * BKT;
  f32x4 acc[4][4] = {};

  for (int kt = 0; kt < K; kt += BKT) {
#pragma unroll
    for (int i = 0; i < 4; ++i) {
      __builtin_amdgcn_global_load_lds(AS1(Ab + (size_t)(i * 32 + srow) * K + kt),
                                       AS3(smA + i * 32 * BKT + ldsbase), 16, 0, 0);
      __builtin_amdgcn_global_load_lds(AS1(Bb + (size_t)(i * 32 + srow) * K + kt),
                                       AS3(smB + i * 32 * BKT + ldsbase), 16, 0, 0);
    }
    __syncthreads();
#pragma unroll
    for (int kk = 0; kk < BKT; kk += 32) {
      bf16x8 af[4], bfr[4];
#pragma unroll
      for (int i = 0; i < 4; ++i) {
        const int ar = wm * 64 + i * 16 + l16;
        af[i]  = *(const bf16x8*)(smA + ar * BKT + ((((kk >> 3) + q) ^ (ar & 7)) * 8));
      }
#pragma unroll
      for (int j = 0; j < 4; ++j) {
        const int br = wn * 64 + j * 16 + l16;
        bfr[j] = *(const bf16x8*)(smB + br * BKT + ((((kk >> 3) + q) ^ (br & 7)) * 8));
      }
#pragma unroll
      for (int i = 0; i < 4; ++i)
#pragma unroll
        for (int j = 0; j < 4; ++j)
          acc[i][j] = __builtin_amdgcn_mfma_f32_16x16x32_bf16(af[i], bfr[j], acc[i][j], 0, 0, 0);
    }
    __syncthreads();
  }

  const int gm0 = by * BM + wm * 64 + q * 4;
  const int gn0 = bx * BN + wn * 64 + l16;
#pragma unroll
  for (int i = 0; i < 4; ++i) {
#pragma unroll
    for (int j = 0; j < 4; ++j) {
      const int n = gn0 + j * 16;
#pragma unroll
      for (int r = 0; r < 4; ++r) {
        const int m = gm0 + i * 16 + r;
        float v = acc[i][j][r];
        if (MODE == 0) {
          outf[(size_t)m * N + n] = v;
        } else if (MODE == 2) {
          float s = 1.0f / (1.0f + expf(-v));
          gate_bf[(size_t)m * N + n] = f2bf(s);
        } else {
          if (n < HD) {
            float g = 0.5f * v * (1.0f + erff(v * 0.70710678118654752f));
            gate_bf[(size_t)m * HD + n] = f2bf(g);
          } else {
            xrec[(size_t)m * HD + (n - HD)] = v;
          }
        }
      }
    }
  }
}

// ---------------------------------------------------------------- 256^2 GEMM
// Stage one half-tile (128 rows x 64 k, bf16) = 2 x global_load_lds(16B).
// src_rc is pre-offset per-thread: matrix + (tile_row0 + tid>>3)*ldg +
// swizzled k-chunk. LDS dest is wave-uniform base; HW adds lane*16B, so the
// linear [row][chunk] layout receives logical chunk (tid&7)^(row&7) at phys
// slot (tid&7)  ==  phys = logical ^ (row&7) (read side matches).
__device__ __forceinline__ void stage_half(const unsigned short* src_rc, int ldg,
                                           int h, int kt, unsigned short* region,
                                           int wid) {
#pragma unroll
  for (int i = 0; i < 2; ++i)
    __builtin_amdgcn_global_load_lds(
        AS1(src_rc + (size_t)(h * 128 + i * 64) * ldg + kt * 64),
        AS3(region + wid * 8 * 64 + i * 64 * 64), 16, 0, 0);
}

// Wave (wm = wid>>2, wn = wid&3) owns C rows {qa*128 + wm*64 + [0,64)} and
// cols {qb*128 + wn*32 + [0,32)} for qa,qb in {0,1} -> 128x64 per wave.
// Phase (qa,qb) touches ONLY A-half qa and B-half qb for ALL waves:
//   consume order per tile T:  p1 A0B0, p2 A0B1, p3 A1B0, p4 A1B1
//   dead-after:                A0@p2, B0@p3, A1/B1@p4
//   stage order:  p1 (T+1).B1 -> buf[nxt]   (region dead since T-1 p4)
//                 p2 (T+1).A1 -> buf[nxt]   (dead since T-1 p4)
//                 p3 (T+2).A0 -> buf[cur]   (dead since T p2)
//                 p4 (T+2).B0 -> buf[cur]   (dead since T p3)
// Boundary wait entering tile T+1: newest in flight = (T+2).B0,(T+2).A0
// (4 loads) -> s_waitcnt vmcnt(4) guarantees (T+1).A1 and older landed.
// Entering the LAST tile nothing newer was issued -> vmcnt(0).
template <int MODE>
__global__ __launch_bounds__(512) void gemm256(
    const unsigned short* __restrict__ A, const unsigned short* __restrict__ Bw,
    unsigned short* __restrict__ gate_bf, float* __restrict__ xrec,
    int N, int K) {
  __shared__ __align__(16) unsigned short sm[2][2][2][128 * 64];  // [buf][A/B][half]
  const int tid  = threadIdx.x;
  const int wid  = tid >> 6;
  const int lane = tid & 63;
  const int wm = wid >> 2, wn = wid & 3;
  const int l16 = lane & 15, q = lane >> 4;

  // T1: bijective XCD swizzle (nwg = 256, 8 XCDs -> each XCD gets one full
  // by-row of 32 blocks; shares the 2 MB A-panel in its private L2).
  const int nx  = gridDim.x;
  const int lin = blockIdx.y * nx + blockIdx.x;
  const int swz = (lin & 7) * ((nx * gridDim.y) >> 3) + (lin >> 3);
  const int bx = swz % nx, by = swz / nx;

  const int srow   = tid >> 3;
  const int schunk = ((tid & 7) ^ (srow & 7)) * 8;
  const unsigned short* Asrc = A  + (size_t)(by * 256 + srow) * K + schunk;
  const unsigned short* Bsrc = Bw + (size_t)(bx * 256 + srow) * K + schunk;

  f32x4 acc[2][2][4][2] = {};
  const int NT = K >> 6;

  // prologue: tile0 {A0,B0,B1,A1} + tile1 {A0,B0}  (12 loads)
  stage_half(Asrc, K, 0, 0, &sm[0][0][0][0], wid);
  stage_half(Bsrc, K, 0, 0, &sm[0][1][0][0], wid);
  stage_half(Bsrc, K, 1, 0, &sm[0][1][1][0], wid);
  stage_half(Asrc, K, 1, 0, &sm[0][0][1][0], wid);
  stage_half(Asrc, K, 0, 1, &sm[1][0][0][0], wid);
  stage_half(Bsrc, K, 0, 1, &sm[1][1][0][0], wid);
  asm volatile("s_waitcnt vmcnt(4)" ::: "memory");  // tile0's 8 loads landed
  __builtin_amdgcn_s_barrier();

#define PHASE(QA, QB, STAGE_STMT)                                              \
  {                                                                            \
    const unsigned short* rgA = &sm[cur][0][QA][0];                            \
    const unsigned short* rgB = &sm[cur][1][QB][0];                            \
    bf16x8 a0[4], a1[4], b0[2], b1[2];                                         \
    _Pragma("unroll")                                                          \
    for (int i = 0; i < 4; ++i) {                                              \
      const int r = wm * 64 + i * 16 + l16;                                    \
      const int s = r & 7;                                                     \
      a0[i] = *(const bf16x8*)(rgA + r * 64 + ((q ^ s) << 3));                 \
      a1[i] = *(const bf16x8*)(rgA + r * 64 + (((4 + q) ^ s) << 3));           \
    }                                                                          \
    _Pragma("unroll")                                                          \
    for (int j = 0; j < 2; ++j) {                                              \
      const int r = wn * 32 + j * 16 + l16;                                    \
      const int s = r & 7;                                                     \
      b0[j] = *(const bf16x8*)(rgB + r * 64 + ((q ^ s) << 3));                 \
      b1[j] = *(const bf16x8*)(rgB + r * 64 + (((4 + q) ^ s) << 3));           \
    }                                                                          \
    STAGE_STMT;                                                                \
    __builtin_amdgcn_s_barrier();                                              \
    __builtin_amdgcn_s_setprio(1);                                             \
    _Pragma("unroll")                                                          \
    for (int i = 0; i < 4; ++i)                                                \
      _Pragma("unroll")                                                        \
      for (int j = 0; j < 2; ++j) {                                            \
        acc[QA][QB][i][j] = __builtin_amdgcn_mfma_f32_16x16x32_bf16(           \
            a0[i], b0[j], acc[QA][QB][i][j], 0, 0, 0);                         \
        acc[QA][QB][i][j] = __builtin_amdgcn_mfma_f32_16x16x32_bf16(           \
            a1[i], b1[j], acc[QA][QB][i][j], 0, 0, 0);                         \
      }                                                                        \
    __builtin_amdgcn_s_setprio(0);                                             \
  }

  for (int T = 0; T < NT; ++T) {
    const int cur = T & 1, nxt = cur ^ 1;
    PHASE(0, 0, if (T + 1 < NT) stage_half(Bsrc, K, 1, T + 1, &sm[nxt][1][1][0], wid))
    __builtin_amdgcn_s_barrier();
    PHASE(0, 1, if (T + 1 < NT) stage_half(Asrc, K, 1, T + 1, &sm[nxt][0][1][0], wid))
    __builtin_amdgcn_s_barrier();
    PHASE(1, 0, if (T + 2 < NT) stage_half(Asrc, K, 0, T + 2, &sm[cur][0][0][0], wid))
    __builtin_amdgcn_s_barrier();
    PHASE(1, 1, if (T + 2 < NT) stage_half(Bsrc, K, 0, T + 2, &sm[cur][1][0][0], wid))
    if (T < NT - 1) {
      if (T == NT - 2) asm volatile("s_waitcnt vmcnt(0)" ::: "memory");
      else             asm volatile("s_waitcnt vmcnt(4)" ::: "memory");
    }
    __builtin_amdgcn_s_barrier();
  }
#undef PHASE

  // epilogue: C/D layout col = lane&15, row = q*4 + reg (m89-verified)
  const int m0 = by * 256 + wm * 64 + q * 4;
  const int n0 = bx * 256 + wn * 32 + l16;
#pragma unroll
  for (int qa = 0; qa < 2; ++qa)
#pragma unroll
    for (int qb = 0; qb < 2; ++qb)
#pragma unroll
      for (int i = 0; i < 4; ++i)
#pragma unroll
        for (int j = 0; j < 2; ++j)
#pragma unroll
          for (int r = 0; r < 4; ++r) {
            const int m = m0 + qa * 128 + i * 16 + r;
            const int n = n0 + qb * 128 + j * 16;
            float v = acc[qa][qb][i][j][r];
            if (MODE == 2) {
              gate_bf[(size_t)m * N + n] = f2bf(1.0f / (1.0f + expf(-v)));
            } else {  // MODE 1: n<HD uniform per (bx,qb) since 256 | HD
              if (n < HD) {
                float g = 0.5f * v * (1.0f + erff(v * 0.70710678118654752f));
                gate_bf[(size_t)m * HD + n] = f2bf(g);
              } else {
                xrec[(size_t)m * HD + (n - HD)] = v;
              }
            }
          }
}

// ---------------------------------------------------------------- conv fuse
__global__ void conv_fuse(const float* __restrict__ cs, const float* xr,
                          const float4* __restrict__ cw, const float* __restrict__ cb,
                          float* __restrict__ ncs, float* xc_out,
                          unsigned short* __restrict__ xc_bf) {
  int t = blockIdx.x * 256 + threadIdx.x;       // t < BSZ*HD
  int h = t & (HD - 1);
  float c0 = cs[3 * t + 0];
  float c1 = cs[3 * t + 1];
  float c2 = cs[3 * t + 2];
  float xv = xr[t];
  float4 w = cw[h];
  float v = fmaf(c0, w.x, fmaf(c1, w.y, fmaf(c2, w.z, fmaf(xv, w.w, cb[h]))));
  ncs[3 * t + 0] = c1;
  ncs[3 * t + 1] = c2;
  ncs[3 * t + 2] = xv;
  xc_out[t] = v;
  xc_bf[t] = f2bf(v);
}

// ---------------------------------------------------------------- rglru fuse
__global__ void rglru_fuse(const unsigned short* __restrict__ gates_bf,
                           const float* __restrict__ av,
                           const float* __restrict__ rs, const float* __restrict__ xc,
                           const unsigned short* __restrict__ gbf,
                           float* __restrict__ nrs, unsigned short* __restrict__ gated) {
  int t = blockIdx.x * 256 + threadIdx.x;       // t < BSZ*HD
  int h = t & (HD - 1);
  int b = t >> 12;
  float it = bf2f(gates_bf[(size_t)b * (2 * HD) + h]);
  float rt = bf2f(gates_bf[(size_t)b * (2 * HD) + HD + h]);
  float at = expf(8.0f * rt * logf(av[h]));
  float mult = sqrtf(fmaxf(0.0f, 1.0f - at * at));
  float x = xc[t];
  float nv = fmaf(rs[t], at, mult * (it * x));
  nrs[t] = nv;
  gated[t] = f2bf(bf2f(gbf[t]) * nv);
}

// ---------------------------------------------------------------- launch
extern "C" void kernel_launch(void* const* d_in, const int* in_sizes, int n_in,
                              void* d_out, int out_size, void* d_ws, size_t ws_size,
                              hipStream_t stream) {
  const float* x  = (const float*)d_in[0];
  const float* cs = (const float*)d_in[1];
  const float* rs = (const float*)d_in[2];
  const float* wf = (const float*)d_in[3];
  const float* cw = (const float*)d_in[4];
  const float* cb = (const float*)d_in[5];
  const float* wg = (const float*)d_in[6];
  const float* av = (const float*)d_in[7];
  const float* wo = (const float*)d_in[8];

  float* out = (float*)d_out;                        // (B,H)
  float* ncs = out + (size_t)BSZ * HD;               // (B,H,3)
  float* nrs = out + (size_t)BSZ * HD * 4;           // (B,H)

  char* ws = (char*)d_ws;
  unsigned short* x_bf   = (unsigned short*)(ws);
  unsigned short* wf_bf  = (unsigned short*)(ws + (size_t)(16u)  * 1048576u);
  unsigned short* wg_bf  = (unsigned short*)(ws + (size_t)(80u)  * 1048576u);
  unsigned short* wo_bf  = (unsigned short*)(ws + (size_t)(144u) * 1048576u);
  unsigned short* gatebf = (unsigned short*)(ws + (size_t)(176u) * 1048576u);
  float*          xrc    = (float*)         (ws + (size_t)(192u) * 1048576u);
  unsigned short* xc_bf  = (unsigned short*)(ws + (size_t)(224u) * 1048576u);
  unsigned short* gates_bf = wf_bf;                  // alias: wf_bf dead after GEMM1
  unsigned short* gated    = x_bf;                   // alias: x_bf dead after GEMM1

  // 1) bf16 conversions
  cvt_f32_to_bf16<<<(BSZ * HD / 4) / 256, 256, 0, stream>>>((const float4*)x,  (ushort4*)x_bf,  BSZ * HD / 4);
  cvt_f32_to_bf16<<<(2 * HD * HD / 4) / 256, 256, 0, stream>>>((const float4*)wf, (ushort4*)wf_bf, 2 * HD * HD / 4);
  cvt_f32_to_bf16<<<(2 * HD * HD / 4) / 256, 256, 0, stream>>>((const float4*)wg, (ushort4*)wg_bf, 2 * HD * HD / 4);
  cvt_f32_to_bf16<<<(HD * HD / 4) / 256, 256, 0, stream>>>((const float4*)wo, (ushort4*)wo_bf, HD * HD / 4);

  // 2) fused = x @ w_fused^T  (256^2 8-phase; grid 32x8 = 256 blocks = 1/CU)
  dim3 g256(2 * HD / 256, BSZ / 256);
  gemm256<1><<<g256, 512, 0, stream>>>(x_bf, wf_bf, gatebf, xrc, 2 * HD, HD);
  // 3) conv + state shift
  conv_fuse<<<(BSZ * HD) / 256, 256, 0, stream>>>(cs, xrc, (const float4*)cw, cb, ncs, xrc, xc_bf);
  // 4) gates = sigmoid(x_conv @ w_gates^T) -> bf16
  gemm256<2><<<g256, 512, 0, stream>>>(xc_bf, wg_bf, gates_bf, nullptr, 2 * HD, HD);
  // 5) rglru recurrence + gated = gate * new_state
  rglru_fuse<<<(BSZ * HD) / 256, 256, 0, stream>>>(gates_bf, av, rs, xrc, gatebf, nrs, gated);
  // 6) out = gated @ w_out^T (128^2 kernel: 512 blocks keeps all CUs busy)
  dim3 g3(HD / BN, BSZ / BM);
  gemm_bt<0><<<g3, dim3(256), 0, stream>>>(gated, wo_bf, out, nullptr, nullptr, BSZ, HD, HD);
}

// Round 2
// 895.830 us; speedup vs baseline: 1.1147x; 1.1147x over previous
//
#include <hip/hip_runtime.h>
#include <cstdint>
#include <cstddef>

// Problem constants (B=2048, H=4096, K=4)
#define HD   4096
#define BSZ  2048

// ---------------------------------------------------------------------------
// R3: gemm256 K-loop restructured to register-cached 4-phase schedule.
// R1 post-mortem: 12 ds_read_b128/phase re-read A-halves per qb and B-halves
// per qa -> 48 reads (48KB)/wave/tile = 384KB/CU per 64KB tile = 6x LDS
// amplification = 123us of pure ds_read at 85B/cyc (m134). Fix: read each
// operand ONCE per tile (24 reads/wave = floor for 2Mx4N wave grid), cache
// in VGPRs (a[4][2] reused across qb; b0/b1[2][2] live all tile), 4 barriers
// per tile instead of 8, counted vmcnt(4)/vmcnt(2) never 0 mid-loop.
// ---------------------------------------------------------------------------
constexpr int BM = 128, BN = 128, BKT = 64;

typedef __bf16 bf16x8 __attribute__((ext_vector_type(8)));
typedef float  f32x4  __attribute__((ext_vector_type(4)));

__device__ __forceinline__ unsigned short f2bf(float f) {
  unsigned u = __float_as_uint(f);
  u += 0x7fffu + ((u >> 16) & 1u);   // RNE
  return (unsigned short)(u >> 16);
}
__device__ __forceinline__ float bf2f(unsigned short s) {
  return __uint_as_float(((unsigned)s) << 16);
}

#define AS1(p) ((__attribute__((address_space(1))) void*)(void*)(p))
#define AS3(p) ((__attribute__((address_space(3))) void*)(p))

// ---------------------------------------------------------------- converts
__global__ void cvt_f32_to_bf16(const float4* __restrict__ src,
                                ushort4* __restrict__ dst, int n4) {
  int i = blockIdx.x * blockDim.x + threadIdx.x;
  if (i >= n4) return;
  float4 v = src[i];
  ushort4 o;
  o.x = f2bf(v.x); o.y = f2bf(v.y); o.z = f2bf(v.z); o.w = f2bf(v.w);
  dst[i] = o;
}

// ---------------------------------------------------------------- 128^2 GEMM
// (kept for GEMM3 / MODE 0 only — harness-verified)
template <int MODE>
__global__ __launch_bounds__(256) void gemm_bt(
    const unsigned short* __restrict__ A, const unsigned short* __restrict__ Bw,
    float* __restrict__ outf, unsigned short* __restrict__ gate_bf,
    float* __restrict__ xrec, int M, int N, int K) {
  __shared__ unsigned short smA[BM * BKT];
  __shared__ unsigned short smB[BN * BKT];
  const int tid  = threadIdx.x;
  const int wid  = tid >> 6;
  const int lane = tid & 63;
  const int wm = wid >> 1, wn = wid & 1;
  const int l16 = lane & 15, q = lane >> 4;
  const int bx = blockIdx.x, by = blockIdx.y;
  const int srow = tid >> 3;
  const int scol = (((tid & 7) ^ ((tid >> 3) & 7)) * 8);
  const unsigned short* Ab = A + (size_t)(by * BM) * K + scol;
  const unsigned short* Bb = Bw + (size_t)(bx * BN) * K + scol;
  const int ldsbase = (wid * 8) * BKT;
  f32x4 acc[4][4] = {};

  for (int kt = 0; kt < K; kt += BKT) {
#pragma unroll
    for (int i = 0; i < 4; ++i) {
      __builtin_amdgcn_global_load_lds(AS1(Ab + (size_t)(i * 32 + srow) * K + kt),
                                       AS3(smA + i * 32 * BKT + ldsbase), 16, 0, 0);
      __builtin_amdgcn_global_load_lds(AS1(Bb + (size_t)(i * 32 + srow) * K + kt),
                                       AS3(smB + i * 32 * BKT + ldsbase), 16, 0, 0);
    }
    __syncthreads();
#pragma unroll
    for (int kk = 0; kk < BKT; kk += 32) {
      bf16x8 af[4], bfr[4];
#pragma unroll
      for (int i = 0; i < 4; ++i) {
        const int ar = wm * 64 + i * 16 + l16;
        af[i]  = *(const bf16x8*)(smA + ar * BKT + ((((kk >> 3) + q) ^ (ar & 7)) * 8));
      }
#pragma unroll
      for (int j = 0; j < 4; ++j) {
        const int br = wn * 64 + j * 16 + l16;
        bfr[j] = *(const bf16x8*)(smB + br * BKT + ((((kk >> 3) + q) ^ (br & 7)) * 8));
      }
#pragma unroll
      for (int i = 0; i < 4; ++i)
#pragma unroll
        for (int j = 0; j < 4; ++j)
          acc[i][j] = __builtin_amdgcn_mfma_f32_16x16x32_bf16(af[i], bfr[j], acc[i][j], 0, 0, 0);
    }
    __syncthreads();
  }

  const int gm0 = by * BM + wm * 64 + q * 4;
  const int gn0 = bx * BN + wn * 64 + l16;
#pragma unroll
  for (int i = 0; i < 4; ++i) {
#pragma unroll
    for (int j = 0; j < 4; ++j) {
      const int n = gn0 + j * 16;
#pragma unroll
      for (int r = 0; r < 4; ++r) {
        const int m = gm0 + i * 16 + r;
        float v = acc[i][j][r];
        if (MODE == 0) {
          outf[(size_t)m * N + n] = v;
        } else if (MODE == 2) {
          float s = 1.0f / (1.0f + expf(-v));
          gate_bf[(size_t)m * N + n] = f2bf(s);
        } else {
          if (n < HD) {
            float g = 0.5f * v * (1.0f + erff(v * 0.70710678118654752f));
            gate_bf[(size_t)m * HD + n] = f2bf(g);
          } else {
            xrec[(size_t)m * HD + (n - HD)] = v;
          }
        }
      }
    }
  }
}

// ---------------------------------------------------------------- 256^2 GEMM
__device__ __forceinline__ void stage_half(const unsigned short* src_rc, int ldg,
                                           int h, int kt, unsigned short* region,
                                           int wid) {
#pragma unroll
  for (int i = 0; i < 2; ++i)
    __builtin_amdgcn_global_load_lds(
        AS1(src_rc + (size_t)(h * 128 + i * 64) * ldg + kt * 64),
        AS3(region + wid * 8 * 64 + i * 64 * 64), 16, 0, 0);
}

// Wave (wm = wid>>2, wn = wid&3) owns C rows {qa*128 + wm*64 + [0,64)} and
// cols {qb*128 + wn*32 + [0,32)}. Per tile: 24 ds_read_b128/wave (floor):
//   p1: read B0,B1 (8) + A0 (8); stage A0(T+1);            barrier; MFMA(0,0)
//   p2: (regs only)              stage B0(T+1); vmcnt(4);  barrier; MFMA(0,1)
//   p3: read A1 (8, reuse a[]);  stage B1(T+1);            barrier; MFMA(1,0)
//   p4: (regs only)              stage A1(T+1); vmcnt(2);  barrier; MFMA(1,1)
// vmcnt ledger (per wave, 2 loads per stage_half):
//   boundary (p4): in-flight [A0,B0,B1,A1](T+1)=8 -> vmcnt(2) retires
//     A0,B0,B1 needed by next p1; A1 still in flight.
//   mid (p2): in-flight [A1(T), A0(T+1), B0(T+1)]=6 -> vmcnt(4) retires A1(T)
//     needed by p3's ds_read. Last tile: only [A1]=2 in flight -> vmcnt(0).
// Region lifetime: all reads of buf[cur] retire by p3 of T (lgkm before MFMA
// use); earliest overwrite of that region is >= p1 of T+1 (stages during T
// go to buf[nxt]) = >=4 barriers later. Wait-before-barrier / read-after-
// barrier preserved for cross-wave gload_lds visibility.
template <int MODE>
__global__ __launch_bounds__(512, 2) void gemm256(
    const unsigned short* __restrict__ A, const unsigned short* __restrict__ Bw,
    unsigned short* __restrict__ gate_bf, float* __restrict__ xrec,
    int N, int K) {
  __shared__ __align__(16) unsigned short sm[2][2][2][128 * 64];  // [buf][A/B][half]
  const int tid  = threadIdx.x;
  const int wid  = tid >> 6;
  const int lane = tid & 63;
  const int wm = wid >> 2, wn = wid & 3;
  const int l16 = lane & 15, q = lane >> 4;

  // T1: bijective XCD swizzle (nwg multiple of 8)
  const int nx  = gridDim.x;
  const int lin = blockIdx.y * nx + blockIdx.x;
  const int swz = (lin & 7) * ((nx * gridDim.y) >> 3) + (lin >> 3);
  const int bx = swz % nx, by = swz / nx;

  const int srow   = tid >> 3;
  const int schunk = ((tid & 7) ^ (srow & 7)) * 8;
  const unsigned short* Asrc = A  + (size_t)(by * 256 + srow) * K + schunk;
  const unsigned short* Bsrc = Bw + (size_t)(bx * 256 + srow) * K + schunk;

  f32x4 acc[2][2][4][2] = {};
  const int NT = K >> 6;

  // prologue: tile0 {A0,B0,B1,A1}; p1 needs A0,B0,B1 -> vmcnt(2)
  stage_half(Asrc, K, 0, 0, &sm[0][0][0][0], wid);
  stage_half(Bsrc, K, 0, 0, &sm[0][1][0][0], wid);
  stage_half(Bsrc, K, 1, 0, &sm[0][1][1][0], wid);
  stage_half(Asrc, K, 1, 0, &sm[0][0][1][0], wid);
  asm volatile("s_waitcnt vmcnt(2)" ::: "memory");
  __builtin_amdgcn_s_barrier();

  for (int T = 0; T < NT; ++T) {
    const int cur = T & 1, nxt = cur ^ 1;
    bf16x8 a[4][2], b0[2][2], b1[2][2];
    // -------- p1: read B0,B1,A0 ; stage A0(T+1) ; MFMA (0,0)
    {
      const unsigned short* rgA  = &sm[cur][0][0][0];
      const unsigned short* rgB0 = &sm[cur][1][0][0];
      const unsigned short* rgB1 = &sm[cur][1][1][0];
#pragma unroll
      for (int j = 0; j < 2; ++j) {
        const int r = wn * 32 + j * 16 + l16;
        const int s = r & 7;
        b0[j][0] = *(const bf16x8*)(rgB0 + r * 64 + ((q ^ s) << 3));
        b0[j][1] = *(const bf16x8*)(rgB0 + r * 64 + (((4 + q) ^ s) << 3));
        b1[j][0] = *(const bf16x8*)(rgB1 + r * 64 + ((q ^ s) << 3));
        b1[j][1] = *(const bf16x8*)(rgB1 + r * 64 + (((4 + q) ^ s) << 3));
      }
#pragma unroll
      for (int i = 0; i < 4; ++i) {
        const int r = wm * 64 + i * 16 + l16;
        const int s = r & 7;
        a[i][0] = *(const bf16x8*)(rgA + r * 64 + ((q ^ s) << 3));
        a[i][1] = *(const bf16x8*)(rgA + r * 64 + (((4 + q) ^ s) << 3));
      }
      if (T + 1 < NT) stage_half(Asrc, K, 0, T + 1, &sm[nxt][0][0][0], wid);
      __builtin_amdgcn_s_barrier();
      __builtin_amdgcn_s_setprio(1);
#pragma unroll
      for (int i = 0; i < 4; ++i)
#pragma unroll
        for (int j = 0; j < 2; ++j) {
          acc[0][0][i][j] = __builtin_amdgcn_mfma_f32_16x16x32_bf16(a[i][0], b0[j][0], acc[0][0][i][j], 0, 0, 0);
          acc[0][0][i][j] = __builtin_amdgcn_mfma_f32_16x16x32_bf16(a[i][1], b0[j][1], acc[0][0][i][j], 0, 0, 0);
        }
      __builtin_amdgcn_s_setprio(0);
    }
    // -------- p2: stage B0(T+1); vmcnt; MFMA (0,1)  (a,b1 from regs)
    {
      if (T + 1 < NT) stage_half(Bsrc, K, 0, T + 1, &sm[nxt][1][0][0], wid);
      if (T == NT - 1) asm volatile("s_waitcnt vmcnt(0)" ::: "memory");
      else             asm volatile("s_waitcnt vmcnt(4)" ::: "memory");
      __builtin_amdgcn_s_barrier();
      __builtin_amdgcn_s_setprio(1);
#pragma unroll
      for (int i = 0; i < 4; ++i)
#pragma unroll
        for (int j = 0; j < 2; ++j) {
          acc[0][1][i][j] = __builtin_amdgcn_mfma_f32_16x16x32_bf16(a[i][0], b1[j][0], acc[0][1][i][j], 0, 0, 0);
          acc[0][1][i][j] = __builtin_amdgcn_mfma_f32_16x16x32_bf16(a[i][1], b1[j][1], acc[0][1][i][j], 0, 0, 0);
        }
      __builtin_amdgcn_s_setprio(0);
    }
    // -------- p3: read A1 (reuse a[]); stage B1(T+1); MFMA (1,0)
    {
      const unsigned short* rgA = &sm[cur][0][1][0];
#pragma unroll
      for (int i = 0; i < 4; ++i) {
        const int r = wm * 64 + i * 16 + l16;
        const int s = r & 7;
        a[i][0] = *(const bf16x8*)(rgA + r * 64 + ((q ^ s) << 3));
        a[i][1] = *(const bf16x8*)(rgA + r * 64 + (((4 + q) ^ s) << 3));
      }
      if (T + 1 < NT) stage_half(Bsrc, K, 1, T + 1, &sm[nxt][1][1][0], wid);
      __builtin_amdgcn_s_barrier();
      __builtin_amdgcn_s_setprio(1);
#pragma unroll
      for (int i = 0; i < 4; ++i)
#pragma unroll
        for (int j = 0; j < 2; ++j) {
          acc[1][0][i][j] = __builtin_amdgcn_mfma_f32_16x16x32_bf16(a[i][0], b0[j][0], acc[1][0][i][j], 0, 0, 0);
          acc[1][0][i][j] = __builtin_amdgcn_mfma_f32_16x16x32_bf16(a[i][1], b0[j][1], acc[1][0][i][j], 0, 0, 0);
        }
      __builtin_amdgcn_s_setprio(0);
    }
    // -------- p4: stage A1(T+1); vmcnt(2); MFMA (1,1)
    {
      if (T + 1 < NT) stage_half(Asrc, K, 1, T + 1, &sm[nxt][0][1][0], wid);
      asm volatile("s_waitcnt vmcnt(2)" ::: "memory");
      __builtin_amdgcn_s_barrier();
      __builtin_amdgcn_s_setprio(1);
#pragma unroll
      for (int i = 0; i < 4; ++i)
#pragma unroll
        for (int j = 0; j < 2; ++j) {
          acc[1][1][i][j] = __builtin_amdgcn_mfma_f32_16x16x32_bf16(a[i][0], b1[j][0], acc[1][1][i][j], 0, 0, 0);
          acc[1][1][i][j] = __builtin_amdgcn_mfma_f32_16x16x32_bf16(a[i][1], b1[j][1], acc[1][1][i][j], 0, 0, 0);
        }
      __builtin_amdgcn_s_setprio(0);
    }
  }

  // epilogue: C/D layout col = lane&15, row = q*4 + reg (m89-verified)
  const int m0 = by * 256 + wm * 64 + q * 4;
  const int n0 = bx * 256 + wn * 32 + l16;
#pragma unroll
  for (int qa = 0; qa < 2; ++qa)
#pragma unroll
    for (int qb = 0; qb < 2; ++qb)
#pragma unroll
      for (int i = 0; i < 4; ++i)
#pragma unroll
        for (int j = 0; j < 2; ++j)
#pragma unroll
          for (int r = 0; r < 4; ++r) {
            const int m = m0 + qa * 128 + i * 16 + r;
            const int n = n0 + qb * 128 + j * 16;
            float v = acc[qa][qb][i][j][r];
            if (MODE == 2) {
              gate_bf[(size_t)m * N + n] = f2bf(1.0f / (1.0f + expf(-v)));
            } else {  // MODE 1: n<HD uniform per (bx,qb) since 256 | HD
              if (n < HD) {
                float g = 0.5f * v * (1.0f + erff(v * 0.70710678118654752f));
                gate_bf[(size_t)m * HD + n] = f2bf(g);
              } else {
                xrec[(size_t)m * HD + (n - HD)] = v;
              }
            }
          }
}

// ---------------------------------------------------------------- conv fuse
__global__ void conv_fuse(const float* __restrict__ cs, const float* xr,
                          const float4* __restrict__ cw, const float* __restrict__ cb,
                          float* __restrict__ ncs, float* xc_out,
                          unsigned short* __restrict__ xc_bf) {
  int t = blockIdx.x * 256 + threadIdx.x;       // t < BSZ*HD
  int h = t & (HD - 1);
  float c0 = cs[3 * t + 0];
  float c1 = cs[3 * t + 1];
  float c2 = cs[3 * t + 2];
  float xv = xr[t];
  float4 w = cw[h];
  float v = fmaf(c0, w.x, fmaf(c1, w.y, fmaf(c2, w.z, fmaf(xv, w.w, cb[h]))));
  ncs[3 * t + 0] = c1;
  ncs[3 * t + 1] = c2;
  ncs[3 * t + 2] = xv;
  xc_out[t] = v;
  xc_bf[t] = f2bf(v);
}

// ---------------------------------------------------------------- rglru fuse
__global__ void rglru_fuse(const unsigned short* __restrict__ gates_bf,
                           const float* __restrict__ av,
                           const float* __restrict__ rs, const float* __restrict__ xc,
                           const unsigned short* __restrict__ gbf,
                           float* __restrict__ nrs, unsigned short* __restrict__ gated) {
  int t = blockIdx.x * 256 + threadIdx.x;       // t < BSZ*HD
  int h = t & (HD - 1);
  int b = t >> 12;
  float it = bf2f(gates_bf[(size_t)b * (2 * HD) + h]);
  float rt = bf2f(gates_bf[(size_t)b * (2 * HD) + HD + h]);
  float at = expf(8.0f * rt * logf(av[h]));
  float mult = sqrtf(fmaxf(0.0f, 1.0f - at * at));
  float x = xc[t];
  float nv = fmaf(rs[t], at, mult * (it * x));
  nrs[t] = nv;
  gated[t] = f2bf(bf2f(gbf[t]) * nv);
}

// ---------------------------------------------------------------- launch
extern "C" void kernel_launch(void* const* d_in, const int* in_sizes, int n_in,
                              void* d_out, int out_size, void* d_ws, size_t ws_size,
                              hipStream_t stream) {
  const float* x  = (const float*)d_in[0];
  const float* cs = (const float*)d_in[1];
  const float* rs = (const float*)d_in[2];
  const float* wf = (const float*)d_in[3];
  const float* cw = (const float*)d_in[4];
  const float* cb = (const float*)d_in[5];
  const float* wg = (const float*)d_in[6];
  const float* av = (const float*)d_in[7];
  const float* wo = (const float*)d_in[8];

  float* out = (float*)d_out;                        // (B,H)
  float* ncs = out + (size_t)BSZ * HD;               // (B,H,3)
  float* nrs = out + (size_t)BSZ * HD * 4;           // (B,H)

  char* ws = (char*)d_ws;
  unsigned short* x_bf   = (unsigned short*)(ws);
  unsigned short* wf_bf  = (unsigned short*)(ws + (size_t)(16u)  * 1048576u);
  unsigned short* wg_bf  = (unsigned short*)(ws + (size_t)(80u)  * 1048576u);
  unsigned short* wo_bf  = (unsigned short*)(ws + (size_t)(144u) * 1048576u);
  unsigned short* gatebf = (unsigned short*)(ws + (size_t)(176u) * 1048576u);
  float*          xrc    = (float*)         (ws + (size_t)(192u) * 1048576u);
  unsigned short* xc_bf  = (unsigned short*)(ws + (size_t)(224u) * 1048576u);
  unsigned short* gates_bf = wf_bf;                  // alias: wf_bf dead after GEMM1
  unsigned short* gated    = x_bf;                   // alias: x_bf dead after GEMM1

  // 1) bf16 conversions
  cvt_f32_to_bf16<<<(BSZ * HD / 4) / 256, 256, 0, stream>>>((const float4*)x,  (ushort4*)x_bf,  BSZ * HD / 4);
  cvt_f32_to_bf16<<<(2 * HD * HD / 4) / 256, 256, 0, stream>>>((const float4*)wf, (ushort4*)wf_bf, 2 * HD * HD / 4);
  cvt_f32_to_bf16<<<(2 * HD * HD / 4) / 256, 256, 0, stream>>>((const float4*)wg, (ushort4*)wg_bf, 2 * HD * HD / 4);
  cvt_f32_to_bf16<<<(HD * HD / 4) / 256, 256, 0, stream>>>((const float4*)wo, (ushort4*)wo_bf, HD * HD / 4);

  // 2) fused = x @ w_fused^T  (256^2 4-phase reg-cached; grid 32x8 = 256)
  dim3 g256(2 * HD / 256, BSZ / 256);
  gemm256<1><<<g256, 512, 0, stream>>>(x_bf, wf_bf, gatebf, xrc, 2 * HD, HD);
  // 3) conv + state shift
  conv_fuse<<<(BSZ * HD) / 256, 256, 0, stream>>>(cs, xrc, (const float4*)cw, cb, ncs, xrc, xc_bf);
  // 4) gates = sigmoid(x_conv @ w_gates^T) -> bf16
  gemm256<2><<<g256, 512, 0, stream>>>(xc_bf, wg_bf, gates_bf, nullptr, 2 * HD, HD);
  // 5) rglru recurrence + gated = gate * new_state
  rglru_fuse<<<(BSZ * HD) / 256, 256, 0, stream>>>(gates_bf, av, rs, xrc, gatebf, nrs, gated);
  // 6) out = gated @ w_out^T (128^2 kernel: 512 blocks keeps all CUs busy)
  dim3 g3(HD / BN, BSZ / BM);
  gemm_bt<0><<<g3, dim3(256), 0, stream>>>(gated, wo_bf, out, nullptr, nullptr, BSZ, HD, HD);
}

// Round 3
// 884.555 us; speedup vs baseline: 1.1289x; 1.0127x over previous
//
#include <hip/hip_runtime.h>
#include <cstdint>
#include <cstddef>

// Problem constants (B=2048, H=4096, K=4)
#define HD   4096
#define BSZ  2048

// ---------------------------------------------------------------------------
// R4: gemm256 K-loop ported to the FAITHFUL m201 8-phase template.
// R2 post-mortem: 4-phase reg-cached = "coarse phase-split" (m196: -7..-27%
// vs 8-phase). Deltas now applied: (1) ONE vmcnt per tile at P4/P8 with
// N=6, retiring loads issued a full tile earlier (deep pipeline, 14 loads
// in flight) instead of two tight waits; (2) exactly one half-tile staged
// per phase (smooth HBM pacing); (3) reads split 12/4/8/0 with the
// template's 2-barrier-per-phase + lgkmcnt(0) + setprio placement.
// Ledger (per-wave instr units, 2 loads per half-tile), steady state:
//   entry: t1.{A0,B0,B1}=6 -> P1 +t1.A1=8 -> P2 +t2.A0=10 -> P3 +t2.B0=12
//   -> P4 +t2.B1=14, vmcnt(6) retires t1 fully; leaves t2.{A0,B0,B1}=6
//   -> P5 +t2.A1=8 -> P6 +t3.A0=10 -> P7 +t3.B0=12 -> P8 +t3.B1=14,
//   vmcnt(6) retires t2; leaves t3.{A0,B0,B1}=6 = next entry. Last iter:
//   no t2/t3 stages -> vmcnt(0) at P4 (P8 trivially).
// Region safety: each LDS region has >=1 full barrier between last ds_read
// (retired at that phase's lgkmcnt(0), all waves by phase-end barrier) and
// its re-staging issue; reads of tile t occur only after the vmcnt+barrier
// that retired t's loads in ALL waves.
// ---------------------------------------------------------------------------
constexpr int BM = 128, BN = 128, BKT = 64;

typedef __bf16 bf16x8 __attribute__((ext_vector_type(8)));
typedef float  f32x4  __attribute__((ext_vector_type(4)));

__device__ __forceinline__ unsigned short f2bf(float f) {
  unsigned u = __float_as_uint(f);
  u += 0x7fffu + ((u >> 16) & 1u);   // RNE
  return (unsigned short)(u >> 16);
}
__device__ __forceinline__ float bf2f(unsigned short s) {
  return __uint_as_float(((unsigned)s) << 16);
}

#define AS1(p) ((__attribute__((address_space(1))) void*)(void*)(p))
#define AS3(p) ((__attribute__((address_space(3))) void*)(p))

// ---------------------------------------------------------------- converts
__global__ void cvt_f32_to_bf16(const float4* __restrict__ src,
                                ushort4* __restrict__ dst, int n4) {
  int i = blockIdx.x * blockDim.x + threadIdx.x;
  if (i >= n4) return;
  float4 v = src[i];
  ushort4 o;
  o.x = f2bf(v.x); o.y = f2bf(v.y); o.z = f2bf(v.z); o.w = f2bf(v.w);
  dst[i] = o;
}

// ---------------------------------------------------------------- 128^2 GEMM
// (kept for GEMM3 / MODE 0 only — harness-verified)
template <int MODE>
__global__ __launch_bounds__(256) void gemm_bt(
    const unsigned short* __restrict__ A, const unsigned short* __restrict__ Bw,
    float* __restrict__ outf, unsigned short* __restrict__ gate_bf,
    float* __restrict__ xrec, int M, int N, int K) {
  __shared__ unsigned short smA[BM * BKT];
  __shared__ unsigned short smB[BN * BKT];
  const int tid  = threadIdx.x;
  const int wid  = tid >> 6;
  const int lane = tid & 63;
  const int wm = wid >> 1, wn = wid & 1;
  const int l16 = lane & 15, q = lane >> 4;
  const int bx = blockIdx.x, by = blockIdx.y;
  const int srow = tid >> 3;
  const int scol = (((tid & 7) ^ ((tid >> 3) & 7)) * 8);
  const unsigned short* Ab = A + (size_t)(by * BM) * K + scol;
  const unsigned short* Bb = Bw + (size_t)(bx * BN) * K + scol;
  const int ldsbase = (wid * 8) * BKT;
  f32x4 acc[4][4] = {};

  for (int kt = 0; kt < K; kt += BKT) {
#pragma unroll
    for (int i = 0; i < 4; ++i) {
      __builtin_amdgcn_global_load_lds(AS1(Ab + (size_t)(i * 32 + srow) * K + kt),
                                       AS3(smA + i * 32 * BKT + ldsbase), 16, 0, 0);
      __builtin_amdgcn_global_load_lds(AS1(Bb + (size_t)(i * 32 + srow) * K + kt),
                                       AS3(smB + i * 32 * BKT + ldsbase), 16, 0, 0);
    }
    __syncthreads();
#pragma unroll
    for (int kk = 0; kk < BKT; kk += 32) {
      bf16x8 af[4], bfr[4];
#pragma unroll
      for (int i = 0; i < 4; ++i) {
        const int ar = wm * 64 + i * 16 + l16;
        af[i]  = *(const bf16x8*)(smA + ar * BKT + ((((kk >> 3) + q) ^ (ar & 7)) * 8));
      }
#pragma unroll
      for (int j = 0; j < 4; ++j) {
        const int br = wn * 64 + j * 16 + l16;
        bfr[j] = *(const bf16x8*)(smB + br * BKT + ((((kk >> 3) + q) ^ (br & 7)) * 8));
      }
#pragma unroll
      for (int i = 0; i < 4; ++i)
#pragma unroll
        for (int j = 0; j < 4; ++j)
          acc[i][j] = __builtin_amdgcn_mfma_f32_16x16x32_bf16(af[i], bfr[j], acc[i][j], 0, 0, 0);
    }
    __syncthreads();
  }

  const int gm0 = by * BM + wm * 64 + q * 4;
  const int gn0 = bx * BN + wn * 64 + l16;
#pragma unroll
  for (int i = 0; i < 4; ++i) {
#pragma unroll
    for (int j = 0; j < 4; ++j) {
      const int n = gn0 + j * 16;
#pragma unroll
      for (int r = 0; r < 4; ++r) {
        const int m = gm0 + i * 16 + r;
        float v = acc[i][j][r];
        if (MODE == 0) {
          outf[(size_t)m * N + n] = v;
        } else if (MODE == 2) {
          float s = 1.0f / (1.0f + expf(-v));
          gate_bf[(size_t)m * N + n] = f2bf(s);
        } else {
          if (n < HD) {
            float g = 0.5f * v * (1.0f + erff(v * 0.70710678118654752f));
            gate_bf[(size_t)m * HD + n] = f2bf(g);
          } else {
            xrec[(size_t)m * HD + (n - HD)] = v;
          }
        }
      }
    }
  }
}

// ---------------------------------------------------------------- 256^2 GEMM
__device__ __forceinline__ void stage_half(const unsigned short* src_rc, int ldg,
                                           int h, int kt, unsigned short* region,
                                           int wid) {
#pragma unroll
  for (int i = 0; i < 2; ++i)
    __builtin_amdgcn_global_load_lds(
        AS1(src_rc + (size_t)(h * 128 + i * 64) * ldg + kt * 64),
        AS3(region + wid * 8 * 64 + i * 64 * 64), 16, 0, 0);
}

template <int MODE>
__global__ __launch_bounds__(512, 2) void gemm256(
    const unsigned short* __restrict__ A, const unsigned short* __restrict__ Bw,
    unsigned short* __restrict__ gate_bf, float* __restrict__ xrec,
    int N, int K) {
  __shared__ __align__(16) unsigned short sm[2][2][2][128 * 64];  // [buf][A/B][half]
  const int tid  = threadIdx.x;
  const int wid  = tid >> 6;
  const int lane = tid & 63;
  const int wm = wid >> 2, wn = wid & 3;
  const int l16 = lane & 15, q = lane >> 4;

  // T1: bijective XCD swizzle (nwg multiple of 8)
  const int nx  = gridDim.x;
  const int lin = blockIdx.y * nx + blockIdx.x;
  const int swz = (lin & 7) * ((nx * gridDim.y) >> 3) + (lin >> 3);
  const int bx = swz % nx, by = swz / nx;

  const int srow   = tid >> 3;
  const int schunk = ((tid & 7) ^ (srow & 7)) * 8;
  const unsigned short* Asrc = A  + (size_t)(by * 256 + srow) * K + schunk;
  const unsigned short* Bsrc = Bw + (size_t)(bx * 256 + srow) * K + schunk;

  f32x4 acc[2][2][4][2] = {};
  const int NT = K >> 6;   // 64, even

  bf16x8 a[4][2], b0[2][2], b1[2][2];

#define BARX() __builtin_amdgcn_s_barrier()
#define LGKM0() asm volatile("s_waitcnt lgkmcnt(0)" ::: "memory")
#define READ_A(BUF, HALF)                                                      \
  {                                                                            \
    const unsigned short* rgA = &sm[BUF][0][HALF][0];                          \
    _Pragma("unroll")                                                          \
    for (int i = 0; i < 4; ++i) {                                              \
      const int r = wm * 64 + i * 16 + l16;                                    \
      const int s = r & 7;                                                     \
      a[i][0] = *(const bf16x8*)(rgA + r * 64 + ((q ^ s) << 3));               \
      a[i][1] = *(const bf16x8*)(rgA + r * 64 + (((4 + q) ^ s) << 3));         \
    }                                                                          \
  }
#define READ_B(BUF, HALF, DST)                                                 \
  {                                                                            \
    const unsigned short* rgB = &sm[BUF][1][HALF][0];                          \
    _Pragma("unroll")                                                          \
    for (int j = 0; j < 2; ++j) {                                              \
      const int r = wn * 32 + j * 16 + l16;                                    \
      const int s = r & 7;                                                     \
      DST[j][0] = *(const bf16x8*)(rgB + r * 64 + ((q ^ s) << 3));             \
      DST[j][1] = *(const bf16x8*)(rgB + r * 64 + (((4 + q) ^ s) << 3));       \
    }                                                                          \
  }
#define MFMA_Q(QA, QB, BB)                                                     \
  __builtin_amdgcn_s_setprio(1);                                               \
  _Pragma("unroll")                                                            \
  for (int i = 0; i < 4; ++i)                                                  \
    _Pragma("unroll")                                                          \
    for (int j = 0; j < 2; ++j) {                                              \
      acc[QA][QB][i][j] = __builtin_amdgcn_mfma_f32_16x16x32_bf16(             \
          a[i][0], BB[j][0], acc[QA][QB][i][j], 0, 0, 0);                      \
      acc[QA][QB][i][j] = __builtin_amdgcn_mfma_f32_16x16x32_bf16(             \
          a[i][1], BB[j][1], acc[QA][QB][i][j], 0, 0, 0);                      \
    }                                                                          \
  __builtin_amdgcn_s_setprio(0)

  // prologue: t0 {A0,B0,B1,A1} + t1 {A0,B0,B1} = 14 loads; vmcnt(6)
  // retires all 8 of t0, leaves t1.{A0,B0,B1}=6 (loop entry invariant).
  stage_half(Asrc, K, 0, 0, &sm[0][0][0][0], wid);
  stage_half(Bsrc, K, 0, 0, &sm[0][1][0][0], wid);
  stage_half(Bsrc, K, 1, 0, &sm[0][1][1][0], wid);
  stage_half(Asrc, K, 1, 0, &sm[0][0][1][0], wid);
  stage_half(Asrc, K, 0, 1, &sm[1][0][0][0], wid);
  stage_half(Bsrc, K, 0, 1, &sm[1][1][0][0], wid);
  stage_half(Bsrc, K, 1, 1, &sm[1][1][1][0], wid);
  asm volatile("s_waitcnt vmcnt(6)" ::: "memory");
  BARX();

  for (int it = 0; it < (NT >> 1); ++it) {
    const int t1 = 2 * it + 1, t2 = 2 * it + 2, t3 = 2 * it + 3;
    // ---- P1: reads A0,B0 (t0=buf0); stage t1.A1 -> buf1.A1
    READ_A(0, 0); READ_B(0, 0, b0);
    stage_half(Asrc, K, 1, t1, &sm[1][0][1][0], wid);
    BARX(); LGKM0();
    MFMA_Q(0, 0, b0);
    BARX();
    // ---- P2: reads B1 (t0); stage t2.A0 -> buf0.A0
    READ_B(0, 1, b1);
    if (t2 < NT) stage_half(Asrc, K, 0, t2, &sm[0][0][0][0], wid);
    BARX(); LGKM0();
    MFMA_Q(0, 1, b1);
    BARX();
    // ---- P3: reads A1 (t0); stage t2.B0 -> buf0.B0
    READ_A(0, 1);
    if (t2 < NT) stage_half(Bsrc, K, 0, t2, &sm[0][1][0][0], wid);
    BARX(); LGKM0();
    MFMA_Q(1, 0, b0);
    BARX();
    // ---- P4: stage t2.B1 -> buf0.B1; vmcnt(6) retires t1 fully
    if (t2 < NT) {
      stage_half(Bsrc, K, 1, t2, &sm[0][1][1][0], wid);
      asm volatile("s_waitcnt vmcnt(6)" ::: "memory");
    } else {
      asm volatile("s_waitcnt vmcnt(0)" ::: "memory");
    }
    BARX();
    MFMA_Q(1, 1, b1);
    BARX();
    // ---- P5: reads A0,B0 (t1=buf1); stage t2.A1 -> buf0.A1
    READ_A(1, 0); READ_B(1, 0, b0);
    if (t2 < NT) stage_half(Asrc, K, 1, t2, &sm[0][0][1][0], wid);
    BARX(); LGKM0();
    MFMA_Q(0, 0, b0);
    BARX();
    // ---- P6: reads B1 (t1); stage t3.A0 -> buf1.A0
    READ_B(1, 1, b1);
    if (t3 < NT) stage_half(Asrc, K, 0, t3, &sm[1][0][0][0], wid);
    BARX(); LGKM0();
    MFMA_Q(0, 1, b1);
    BARX();
    // ---- P7: reads A1 (t1); stage t3.B0 -> buf1.B0
    READ_A(1, 1);
    if (t3 < NT) stage_half(Bsrc, K, 0, t3, &sm[1][1][0][0], wid);
    BARX(); LGKM0();
    MFMA_Q(1, 0, b0);
    BARX();
    // ---- P8: stage t3.B1 -> buf1.B1; vmcnt(6) retires t2 fully
    if (t3 < NT) {
      stage_half(Bsrc, K, 1, t3, &sm[1][1][1][0], wid);
      asm volatile("s_waitcnt vmcnt(6)" ::: "memory");
    } else {
      asm volatile("s_waitcnt vmcnt(0)" ::: "memory");
    }
    BARX();
    MFMA_Q(1, 1, b1);
    BARX();
  }
#undef MFMA_Q
#undef READ_B
#undef READ_A
#undef LGKM0
#undef BARX

  // epilogue: C/D layout col = lane&15, row = q*4 + reg (m89-verified)
  const int m0 = by * 256 + wm * 64 + q * 4;
  const int n0 = bx * 256 + wn * 32 + l16;
#pragma unroll
  for (int qa = 0; qa < 2; ++qa)
#pragma unroll
    for (int qb = 0; qb < 2; ++qb)
#pragma unroll
      for (int i = 0; i < 4; ++i)
#pragma unroll
        for (int j = 0; j < 2; ++j)
#pragma unroll
          for (int r = 0; r < 4; ++r) {
            const int m = m0 + qa * 128 + i * 16 + r;
            const int n = n0 + qb * 128 + j * 16;
            float v = acc[qa][qb][i][j][r];
            if (MODE == 2) {
              gate_bf[(size_t)m * N + n] = f2bf(1.0f / (1.0f + expf(-v)));
            } else {  // MODE 1: n<HD uniform per (bx,qb) since 256 | HD
              if (n < HD) {
                float g = 0.5f * v * (1.0f + erff(v * 0.70710678118654752f));
                gate_bf[(size_t)m * HD + n] = f2bf(g);
              } else {
                xrec[(size_t)m * HD + (n - HD)] = v;
              }
            }
          }
}

// ---------------------------------------------------------------- conv fuse
__global__ void conv_fuse(const float* __restrict__ cs, const float* xr,
                          const float4* __restrict__ cw, const float* __restrict__ cb,
                          float* __restrict__ ncs, float* xc_out,
                          unsigned short* __restrict__ xc_bf) {
  int t = blockIdx.x * 256 + threadIdx.x;       // t < BSZ*HD
  int h = t & (HD - 1);
  float c0 = cs[3 * t + 0];
  float c1 = cs[3 * t + 1];
  float c2 = cs[3 * t + 2];
  float xv = xr[t];
  float4 w = cw[h];
  float v = fmaf(c0, w.x, fmaf(c1, w.y, fmaf(c2, w.z, fmaf(xv, w.w, cb[h]))));
  ncs[3 * t + 0] = c1;
  ncs[3 * t + 1] = c2;
  ncs[3 * t + 2] = xv;
  xc_out[t] = v;
  xc_bf[t] = f2bf(v);
}

// ---------------------------------------------------------------- rglru fuse
__global__ void rglru_fuse(const unsigned short* __restrict__ gates_bf,
                           const float* __restrict__ av,
                           const float* __restrict__ rs, const float* __restrict__ xc,
                           const unsigned short* __restrict__ gbf,
                           float* __restrict__ nrs, unsigned short* __restrict__ gated) {
  int t = blockIdx.x * 256 + threadIdx.x;       // t < BSZ*HD
  int h = t & (HD - 1);
  int b = t >> 12;
  float it = bf2f(gates_bf[(size_t)b * (2 * HD) + h]);
  float rt = bf2f(gates_bf[(size_t)b * (2 * HD) + HD + h]);
  float at = expf(8.0f * rt * logf(av[h]));
  float mult = sqrtf(fmaxf(0.0f, 1.0f - at * at));
  float x = xc[t];
  float nv = fmaf(rs[t], at, mult * (it * x));
  nrs[t] = nv;
  gated[t] = f2bf(bf2f(gbf[t]) * nv);
}

// ---------------------------------------------------------------- launch
extern "C" void kernel_launch(void* const* d_in, const int* in_sizes, int n_in,
                              void* d_out, int out_size, void* d_ws, size_t ws_size,
                              hipStream_t stream) {
  const float* x  = (const float*)d_in[0];
  const float* cs = (const float*)d_in[1];
  const float* rs = (const float*)d_in[2];
  const float* wf = (const float*)d_in[3];
  const float* cw = (const float*)d_in[4];
  const float* cb = (const float*)d_in[5];
  const float* wg = (const float*)d_in[6];
  const float* av = (const float*)d_in[7];
  const float* wo = (const float*)d_in[8];

  float* out = (float*)d_out;                        // (B,H)
  float* ncs = out + (size_t)BSZ * HD;               // (B,H,3)
  float* nrs = out + (size_t)BSZ * HD * 4;           // (B,H)

  char* ws = (char*)d_ws;
  unsigned short* x_bf   = (unsigned short*)(ws);
  unsigned short* wf_bf  = (unsigned short*)(ws + (size_t)(16u)  * 1048576u);
  unsigned short* wg_bf  = (unsigned short*)(ws + (size_t)(80u)  * 1048576u);
  unsigned short* wo_bf  = (unsigned short*)(ws + (size_t)(144u) * 1048576u);
  unsigned short* gatebf = (unsigned short*)(ws + (size_t)(176u) * 1048576u);
  float*          xrc    = (float*)         (ws + (size_t)(192u) * 1048576u);
  unsigned short* xc_bf  = (unsigned short*)(ws + (size_t)(224u) * 1048576u);
  unsigned short* gates_bf = wf_bf;                  // alias: wf_bf dead after GEMM1
  unsigned short* gated    = x_bf;                   // alias: x_bf dead after GEMM1

  // 1) bf16 conversions
  cvt_f32_to_bf16<<<(BSZ * HD / 4) / 256, 256, 0, stream>>>((const float4*)x,  (ushort4*)x_bf,  BSZ * HD / 4);
  cvt_f32_to_bf16<<<(2 * HD * HD / 4) / 256, 256, 0, stream>>>((const float4*)wf, (ushort4*)wf_bf, 2 * HD * HD / 4);
  cvt_f32_to_bf16<<<(2 * HD * HD / 4) / 256, 256, 0, stream>>>((const float4*)wg, (ushort4*)wg_bf, 2 * HD * HD / 4);
  cvt_f32_to_bf16<<<(HD * HD / 4) / 256, 256, 0, stream>>>((const float4*)wo, (ushort4*)wo_bf, HD * HD / 4);

  // 2) fused = x @ w_fused^T  (256^2 8-phase; grid 32x8 = 256 blocks)
  dim3 g256(2 * HD / 256, BSZ / 256);
  gemm256<1><<<g256, 512, 0, stream>>>(x_bf, wf_bf, gatebf, xrc, 2 * HD, HD);
  // 3) conv + state shift
  conv_fuse<<<(BSZ * HD) / 256, 256, 0, stream>>>(cs, xrc, (const float4*)cw, cb, ncs, xrc, xc_bf);
  // 4) gates = sigmoid(x_conv @ w_gates^T) -> bf16
  gemm256<2><<<g256, 512, 0, stream>>>(xc_bf, wg_bf, gates_bf, nullptr, 2 * HD, HD);
  // 5) rglru recurrence + gated = gate * new_state
  rglru_fuse<<<(BSZ * HD) / 256, 256, 0, stream>>>(gates_bf, av, rs, xrc, gatebf, nrs, gated);
  // 6) out = gated @ w_out^T (128^2 kernel: 512 blocks keeps all CUs busy)
  dim3 g3(HD / BN, BSZ / BM);
  gemm_bt<0><<<g3, dim3(256), 0, stream>>>(gated, wo_bf, out, nullptr, nullptr, BSZ, HD, HD);
}